// Round 1
// baseline (697.320 us; speedup 1.0000x reference)
//
#include <hip/hip_runtime.h>

// CropSplitGT: out[h,w,i] = data[h,w,i] if (w,h) inside roi box i else 0.
// data layout (H, W, N) with N innermost; rois layout (4, N) = [x1; y1; x2; y2].
// Memory-bound masked copy. float4 over the N axis (N=400 -> 100 float4/pixel).
// Skip the data load when all 4 lanes' masks are false (~66% of float4s given
// ~10% mean box coverage) -> exec-masked load saves HBM fetch on all-inactive
// cache lines. Write is unconditional (d_out poisoned with 0xAA).

constexpr int kH = 512;
constexpr int kW = 512;
constexpr int kN = 400;
constexpr int kN4 = kN / 4;                       // 100 float4 per pixel
constexpr int kTotal4 = kH * kW * kN4;            // 26,214,400
constexpr int kBlock = 256;
constexpr int kGrid = kTotal4 / kBlock;           // 102,400 (exact)

__global__ __launch_bounds__(kBlock) void crop_split_gt_kernel(
    const float4* __restrict__ data4,
    const float* __restrict__ rois,
    float4* __restrict__ out4)
{
    const int t = blockIdx.x * kBlock + threadIdx.x;   // grid is exact, no tail

    const int i4    = t % kN4;        // float4 index along N
    const int pixel = t / kN4;        // h*W + w
    const float wf = (float)(pixel % kW);
    const float hf = (float)(pixel / kW);
    const int i = i4 * 4;

    // rois rows are 400 floats apart (1600 B) -> 16B-aligned float4 loads.
    const float4 x1 = *(const float4*)(rois + 0 * kN + i);
    const float4 y1 = *(const float4*)(rois + 1 * kN + i);
    const float4 x2 = *(const float4*)(rois + 2 * kN + i);
    const float4 y2 = *(const float4*)(rois + 3 * kN + i);

    const bool m0 = (wf >= x1.x) && (wf <= x2.x) && (hf >= y1.x) && (hf <= y2.x);
    const bool m1 = (wf >= x1.y) && (wf <= x2.y) && (hf >= y1.y) && (hf <= y2.y);
    const bool m2 = (wf >= x1.z) && (wf <= x2.z) && (hf >= y1.z) && (hf <= y2.z);
    const bool m3 = (wf >= x1.w) && (wf <= x2.w) && (hf >= y1.w) && (hf <= y2.w);

    float4 o = {0.f, 0.f, 0.f, 0.f};
    if (m0 | m1 | m2 | m3) {
        const float4 d = data4[t];    // exec-masked: all-inactive lines not fetched
        if (m0) o.x = d.x;
        if (m1) o.y = d.y;
        if (m2) o.z = d.z;
        if (m3) o.w = d.w;
    }
    out4[t] = o;
}

extern "C" void kernel_launch(void* const* d_in, const int* in_sizes, int n_in,
                              void* d_out, int out_size, void* d_ws, size_t ws_size,
                              hipStream_t stream) {
    const float4* data4 = (const float4*)d_in[0];
    const float*  rois  = (const float*)d_in[1];
    // d_in[2] = c (unused by the GT variant)
    float4* out4 = (float4*)d_out;

    crop_split_gt_kernel<<<kGrid, kBlock, 0, stream>>>(data4, rois, out4);
}